// Round 4
// baseline (266.261 us; speedup 1.0000x reference)
//
#include <hip/hip_runtime.h>

// PyramidROIAlign: B=2, N=1000, C=256, pool 7x7, levels p2..p5 (256,128,64,32), NHWC fp32.
//
// Two-kernel scheme:
//  1) sort_boxes_kernel: single block, counting-sorts the 2000 boxes by
//     (batch, Morton8 of box center) into a permutation in d_ws (~3 us).
//  2) roi_align_kernel: persistent 2048x256; sorted cells partitioned per XCD
//     (blockIdx%8 = HW round-robin XCD assignment). CELLS_PER_WAVE=1: at any instant
//     an XCD's 1024 waves cover 1024 *contiguous* sorted cells ~= 21 Morton-adjacent
//     boxes ~= 2-4 MB feature footprint -> fits the XCD's private 4 MB L2, so the ~3x
//     cross-box corner-read reuse is served by L2 instead of crossing the fabric
//     (fabric ~6.3 TB/s is the measured wall: 490 MB issued / 80 us = 6.1 TB/s).
// Output addressing uses original cell ids -> bit-identical to unsorted order.

#define NB 2
#define NN 1000
#define NBOX (NB * NN)
#define NC 256
#define NCELLS (NBOX * 49)            // 98000
#define WAVES_PER_BLOCK 4
#define NBLOCKS 2048
#define NXCD 8
#define BLOCKS_PER_XCD (NBLOCKS / NXCD)                    // 256
#define WAVES_PER_XCD (BLOCKS_PER_XCD * WAVES_PER_BLOCK)   // 1024
#define CELLS_PER_XCD (NCELLS / NXCD)                      // 12250 exact

typedef float vfloat4 __attribute__((ext_vector_type(4)));

__device__ __forceinline__ int box_bin(const float* __restrict__ boxes, int i)
{
    const vfloat4 bx = *(const vfloat4*)(boxes + (size_t)i * 4);
    const float cy = 0.5f * (bx.x + bx.z);
    const float cx = 0.5f * (bx.y + bx.w);
    const int yb = min(15, max(0, (int)(cy * 16.0f)));
    const int xb = min(15, max(0, (int)(cx * 16.0f)));
    int m = 0;
#pragma unroll
    for (int k = 0; k < 4; ++k)
        m |= (((yb >> k) & 1) << (2 * k + 1)) | (((xb >> k) & 1) << (2 * k));
    return ((i / NN) << 8) | m;          // batch-major, Morton within batch
}

__global__ __launch_bounds__(256) void sort_boxes_kernel(
    const float* __restrict__ boxes, int* __restrict__ perm)
{
    __shared__ int s_cnt[512];
    const int tid = threadIdx.x;
    for (int i = tid; i < 512; i += 256) s_cnt[i] = 0;
    __syncthreads();

    // histogram
    for (int i = tid; i < NBOX; i += 256)
        atomicAdd(&s_cnt[box_bin(boxes, i)], 1);
    __syncthreads();

    // exclusive prefix over 512 bins, wave 0 only (8 bins per lane + wave scan)
    if (tid < 64) {
        int v[8];
        int part = 0;
#pragma unroll
        for (int k = 0; k < 8; ++k) { v[k] = s_cnt[tid * 8 + k]; part += v[k]; }
        int incl = part;
#pragma unroll
        for (int d = 1; d < 64; d <<= 1) {
            const int n = __shfl_up(incl, d);
            if (tid >= d) incl += n;
        }
        int excl = incl - part;
#pragma unroll
        for (int k = 0; k < 8; ++k) { const int t = v[k]; s_cnt[tid * 8 + k] = excl; excl += t; }
    }
    __syncthreads();

    // scatter (recompute bin -> no runtime-indexed register arrays)
    for (int i = tid; i < NBOX; i += 256) {
        const int pos = atomicAdd(&s_cnt[box_bin(boxes, i)], 1);
        perm[pos] = i;
    }
}

__device__ __forceinline__ void cell_setup2(
    int bn, int pxy,                    // wave-uniform
    const float* __restrict__ boxes,
    const float* __restrict__ p2, const float* __restrict__ p3,
    const float* __restrict__ p4, const float* __restrict__ p5,
    const vfloat4*& a00, const vfloat4*& a01, const vfloat4*& a10, const vfloat4*& a11,
    float& wx, float& wy)
{
    const int py = pxy / 7;
    const int px = pxy % 7;
    const int b  = bn / NN;

    const vfloat4 bx = *(const vfloat4*)(boxes + (size_t)bn * 4);
    const float y1 = bx.x, x1 = bx.y, y2 = bx.z, x2 = bx.w;
    const float h = y2 - y1, w = x2 - x1;

    // roi_level = clip(round(log2(sqrt(max(h*w,1e-12)) / (224/1024))), 2, 5); rintf = half-to-even.
    const float roi = log2f(sqrtf(fmaxf(h * w, 1e-12f)) * (1024.0f / 224.0f));
    int lvl = (int)rintf(roi);
    lvl = min(5, max(2, lvl));

    const float* feat;
    int H;
    switch (lvl) {
        case 2:  feat = p2; H = 256; break;
        case 3:  feat = p3; H = 128; break;
        case 4:  feat = p4; H = 64;  break;
        default: feat = p5; H = 32;  break;
    }
    const int W = H;

    const float ys = (y1 + h * ((float)py * (1.0f / 6.0f))) * (float)(H - 1);
    const float xs = (x1 + w * ((float)px * (1.0f / 6.0f))) * (float)(W - 1);
    const float y0f = floorf(ys), x0f = floorf(xs);
    wy = ys - y0f;
    wx = xs - x0f;
    const int y0 = min(H - 1, max(0, (int)y0f));
    const int yb = min(H - 1, max(0, (int)y0f + 1));
    const int x0 = min(W - 1, max(0, (int)x0f));
    const int xb = min(W - 1, max(0, (int)x0f + 1));

    const size_t base = (size_t)b * H * W * NC;
    a00 = (const vfloat4*)(feat + base + ((size_t)y0 * W + x0) * NC);
    a01 = (const vfloat4*)(feat + base + ((size_t)y0 * W + xb) * NC);
    a10 = (const vfloat4*)(feat + base + ((size_t)yb * W + x0) * NC);
    a11 = (const vfloat4*)(feat + base + ((size_t)yb * W + xb) * NC);
}

__device__ __forceinline__ vfloat4 bilerp4(vfloat4 v00, vfloat4 v01, vfloat4 v10, vfloat4 v11,
                                           float wx, float wy)
{
    vfloat4 top = v00 + wx * (v01 - v00);
    vfloat4 bot = v10 + wx * (v11 - v10);
    return top + wy * (bot - top);
}

__global__ __launch_bounds__(256) void roi_align_kernel(
    const float* __restrict__ boxes,
    const float* __restrict__ p2,
    const float* __restrict__ p3,
    const float* __restrict__ p4,
    const float* __restrict__ p5,
    const int* __restrict__ perm,     // may be null -> identity order
    float* __restrict__ out)
{
    const int lane = threadIdx.x & 63;
    const int wave = threadIdx.x >> 6;
    const int xcd  = blockIdx.x & (NXCD - 1);          // HW round-robin XCD assignment
    const int wl   = (blockIdx.x >> 3) * WAVES_PER_BLOCK + wave;   // 0..1023 within XCD
    const int start = xcd * CELLS_PER_XCD;
    const int end   = start + CELLS_PER_XCD;

    // One cell per wave per iteration: the XCD's 1024 waves cover a contiguous
    // 1024-cell (~21-box, ~2-4 MB) window that fits the private 4 MB L2.
    for (int c = start + wl; c < end; c += WAVES_PER_XCD) {
        const int sc  = __builtin_amdgcn_readfirstlane(c);
        const int bns = sc / 49;
        const int pxy = sc - bns * 49;
        int bn = perm ? perm[bns] : bns;
        bn = __builtin_amdgcn_readfirstlane(bn);

        const vfloat4 *a00, *a01, *a10, *a11;
        float wx, wy;
        cell_setup2(bn, pxy, boxes, p2, p3, p4, p5, a00, a01, a10, a11, wx, wy);

        const vfloat4 v00 = a00[lane];
        const vfloat4 v01 = a01[lane];
        const vfloat4 v10 = a10[lane];
        const vfloat4 v11 = a11[lane];

        const vfloat4 r = bilerp4(v00, v01, v10, v11, wx, wy);
        vfloat4* o = (vfloat4*)(out + (size_t)(bn * 49 + pxy) * NC) + lane;
        __builtin_nontemporal_store(r, o);
    }
}

extern "C" void kernel_launch(void* const* d_in, const int* in_sizes, int n_in,
                              void* d_out, int out_size, void* d_ws, size_t ws_size,
                              hipStream_t stream) {
    const float* boxes = (const float*)d_in[0];
    const float* p2    = (const float*)d_in[1];
    const float* p3    = (const float*)d_in[2];
    const float* p4    = (const float*)d_in[3];
    const float* p5    = (const float*)d_in[4];
    float* out = (float*)d_out;

    const int* perm = nullptr;
    if (d_ws != nullptr && ws_size >= NBOX * sizeof(int)) {
        sort_boxes_kernel<<<1, 256, 0, stream>>>(boxes, (int*)d_ws);
        perm = (const int*)d_ws;
    }
    roi_align_kernel<<<NBLOCKS, 256, 0, stream>>>(boxes, p2, p3, p4, p5, perm, out);
}

// Round 5
// 257.740 us; speedup vs baseline: 1.0331x; 1.0331x over previous
//
#include <hip/hip_runtime.h>

// PyramidROIAlign: B=2, N=1000, C=256, pool 7x7, levels p2..p5 (256,128,64,32), NHWC fp32.
// Persistent grid-stride kernel: 2048 blocks x 256 threads. Each wave processes 4 cells
// per iteration (16 corner loads in flight). Cell index is wave-uniform (readfirstlane)
// so setup scalarizes to SALU/SGPR. lane = float4 channel group. Non-temporal output
// stores. No sort/permutation: measured A/B (rounds 2-4) showed Morton+XCD partitioning
// buys zero kernel time and costs ~8 us of extra dispatch.
//
// Roofline accounting (measured): issued traffic = 98000 x (4KB read + 1KB write)
// = 490 MB; kernel 80.8 us -> 6.06 TB/s = 96% of the 6.3 TB/s achievable device BW.

#define NB 2
#define NN 1000
#define NC 256
#define NCELLS (NB * NN * 49)        // 98000
#define CELLS_PER_WAVE 4
#define WAVES_PER_BLOCK 4
#define NBLOCKS 2048
#define TOTAL_WAVES (NBLOCKS * WAVES_PER_BLOCK)   // 8192
#define NGROUPS (NCELLS / CELLS_PER_WAVE)         // 24500 (exact)

typedef float vfloat4 __attribute__((ext_vector_type(4)));   // clang-native, ok for nontemporal builtins

__device__ __forceinline__ void cell_setup(
    int cell,                      // wave-uniform (readfirstlane'd by caller)
    const float* __restrict__ boxes,
    const float* __restrict__ p2, const float* __restrict__ p3,
    const float* __restrict__ p4, const float* __restrict__ p5,
    const vfloat4*& a00, const vfloat4*& a01, const vfloat4*& a10, const vfloat4*& a11,
    float& wx, float& wy)
{
    const int pxy = cell % 49;
    const int bn  = cell / 49;
    const int py  = pxy / 7;
    const int px  = pxy % 7;
    const int b   = bn / NN;

    const vfloat4 bx = *(const vfloat4*)(boxes + (size_t)bn * 4);
    const float y1 = bx.x, x1 = bx.y, y2 = bx.z, x2 = bx.w;
    const float h = y2 - y1, w = x2 - x1;

    // roi_level = clip(round(log2(sqrt(max(h*w,1e-12)) / (224/1024))), 2, 5); rintf = half-to-even.
    const float roi = log2f(sqrtf(fmaxf(h * w, 1e-12f)) * (1024.0f / 224.0f));
    int lvl = (int)rintf(roi);
    lvl = min(5, max(2, lvl));

    const float* feat;
    int H;
    switch (lvl) {
        case 2:  feat = p2; H = 256; break;
        case 3:  feat = p3; H = 128; break;
        case 4:  feat = p4; H = 64;  break;
        default: feat = p5; H = 32;  break;
    }
    const int W = H;

    const float ys = (y1 + h * ((float)py * (1.0f / 6.0f))) * (float)(H - 1);
    const float xs = (x1 + w * ((float)px * (1.0f / 6.0f))) * (float)(W - 1);
    const float y0f = floorf(ys), x0f = floorf(xs);
    wy = ys - y0f;
    wx = xs - x0f;
    const int y0 = min(H - 1, max(0, (int)y0f));
    const int yb = min(H - 1, max(0, (int)y0f + 1));
    const int x0 = min(W - 1, max(0, (int)x0f));
    const int xb = min(W - 1, max(0, (int)x0f + 1));

    const size_t base = (size_t)b * H * W * NC;
    a00 = (const vfloat4*)(feat + base + ((size_t)y0 * W + x0) * NC);
    a01 = (const vfloat4*)(feat + base + ((size_t)y0 * W + xb) * NC);
    a10 = (const vfloat4*)(feat + base + ((size_t)yb * W + x0) * NC);
    a11 = (const vfloat4*)(feat + base + ((size_t)yb * W + xb) * NC);
}

__device__ __forceinline__ vfloat4 bilerp4(vfloat4 v00, vfloat4 v01, vfloat4 v10, vfloat4 v11,
                                           float wx, float wy)
{
    vfloat4 top = v00 + wx * (v01 - v00);
    vfloat4 bot = v10 + wx * (v11 - v10);
    return top + wy * (bot - top);
}

__global__ __launch_bounds__(256) void roi_align_kernel(
    const float* __restrict__ boxes,
    const float* __restrict__ p2,
    const float* __restrict__ p3,
    const float* __restrict__ p4,
    const float* __restrict__ p5,
    float* __restrict__ out)
{
    const int lane = threadIdx.x & 63;
    const int wave = threadIdx.x >> 6;
    const int wid  = blockIdx.x * WAVES_PER_BLOCK + wave;

    for (int g = wid; g < NGROUPS; g += TOTAL_WAVES) {
        const int cbase = g * CELLS_PER_WAVE;

        const vfloat4* a00[CELLS_PER_WAVE];
        const vfloat4* a01[CELLS_PER_WAVE];
        const vfloat4* a10[CELLS_PER_WAVE];
        const vfloat4* a11[CELLS_PER_WAVE];
        float wx[CELLS_PER_WAVE], wy[CELLS_PER_WAVE];

#pragma unroll
        for (int i = 0; i < CELLS_PER_WAVE; ++i) {
            // cell index is wave-uniform; certify it so setup scalarizes to SALU/SGPR.
            const int cell = __builtin_amdgcn_readfirstlane(cbase + i);
            cell_setup(cell, boxes, p2, p3, p4, p5,
                       a00[i], a01[i], a10[i], a11[i], wx[i], wy[i]);
        }

        // Issue all 16 corner loads before any use -> 16 outstanding vmem per wave.
        vfloat4 v00[CELLS_PER_WAVE], v01[CELLS_PER_WAVE], v10[CELLS_PER_WAVE], v11[CELLS_PER_WAVE];
#pragma unroll
        for (int i = 0; i < CELLS_PER_WAVE; ++i) {
            v00[i] = a00[i][lane];
            v01[i] = a01[i][lane];
            v10[i] = a10[i][lane];
            v11[i] = a11[i][lane];
        }

#pragma unroll
        for (int i = 0; i < CELLS_PER_WAVE; ++i) {
            const vfloat4 r = bilerp4(v00[i], v01[i], v10[i], v11[i], wx[i], wy[i]);
            vfloat4* o = (vfloat4*)(out + (size_t)(cbase + i) * NC) + lane;
            __builtin_nontemporal_store(r, o);
        }
    }
}

extern "C" void kernel_launch(void* const* d_in, const int* in_sizes, int n_in,
                              void* d_out, int out_size, void* d_ws, size_t ws_size,
                              hipStream_t stream) {
    const float* boxes = (const float*)d_in[0];
    const float* p2    = (const float*)d_in[1];
    const float* p3    = (const float*)d_in[2];
    const float* p4    = (const float*)d_in[3];
    const float* p5    = (const float*)d_in[4];
    float* out = (float*)d_out;

    roi_align_kernel<<<NBLOCKS, 256, 0, stream>>>(boxes, p2, p3, p4, p5, out);
}